// Round 4
// baseline (442.364 us; speedup 1.0000x reference)
//
#include <hip/hip_runtime.h>

#define NN 50000
#define NE 800000

__device__ inline float rlf(float v, int l) {
    return __int_as_float(__builtin_amdgcn_readlane(__float_as_int(v), l));
}

// ---------------- CSR build ----------------
__global__ void k_hist(const int* __restrict__ dst, int* __restrict__ cnt) {
    int e = blockIdx.x * 256 + threadIdx.x;
    if (e < NE) atomicAdd(&cnt[dst[e]], 1);
}

// disq = 1/sqrt(deg+1), sq = sqrt(deg+1)
__global__ void k_disq(const int* __restrict__ cnt, float* __restrict__ disq,
                       float* __restrict__ sq) {
    int i = blockIdx.x * 256 + threadIdx.x;
    if (i < NN) {
        float d = (float)cnt[i] + 1.0f;
        float r = rsqrtf(d);
        disq[i] = r;
        sq[i] = d * r;  // sqrt(d)
    }
}

// single-block inclusive scan: rowptr[i+1] = sum(cnt[0..i]), rowptr[0] = 0
__global__ __launch_bounds__(1024) void k_scan(const int* __restrict__ cnt,
                                               int* __restrict__ rowptr) {
    __shared__ int wsum[16];
    __shared__ int carry;
    int t = threadIdx.x, wave = t >> 6, lane = t & 63;
    if (t == 0) { carry = 0; rowptr[0] = 0; }
    __syncthreads();
    for (int base = 0; base < NN; base += 1024) {
        int i = base + t;
        int x = (i < NN) ? cnt[i] : 0;
        for (int off = 1; off < 64; off <<= 1) {
            int y = __shfl_up(x, off, 64);
            if (lane >= off) x += y;
        }
        if (lane == 63) wsum[wave] = x;
        __syncthreads();
        if (wave == 0 && lane < 16) {
            int w = wsum[lane];
            for (int off = 1; off < 16; off <<= 1) {
                int y = __shfl_up(w, off, 16);
                if (lane >= off) w += y;
            }
            wsum[lane] = w;
        }
        __syncthreads();
        int incl = carry + ((wave > 0) ? wsum[wave - 1] : 0) + x;
        if (i < NN) rowptr[i + 1] = incl;
        __syncthreads();
        if (t == 1023) carry = incl;
        __syncthreads();
    }
}

__global__ void k_fill(const int* __restrict__ src, const int* __restrict__ dst,
                       const int* __restrict__ rowptr, int* __restrict__ cur,
                       int* __restrict__ esrc) {
    int e = blockIdx.x * 256 + threadIdx.x;
    if (e < NE) {
        int d = dst[e];
        int pos = rowptr[d] + atomicAdd(&cur[d], 1);
        esrc[pos] = src[e];
    }
}

// ---------------- fc stack: Xs = disq * (relu(nf@W1+b1)@W2+b2) ----------------
// wave per node; W1/W2 columns register-resident; x broadcast via readlane
__global__ __launch_bounds__(256) void k_fc(
    const float* __restrict__ nf,
    const float* __restrict__ W1, const float* __restrict__ b1,
    const float* __restrict__ W2, const float* __restrict__ b2,
    const float* __restrict__ disq, float* __restrict__ Xs) {
    int lane = threadIdx.x & 63;
    int c = lane & 31, h = lane >> 5;
    int wid = (blockIdx.x * 256 + threadIdx.x) >> 6;
    int nwaves = (gridDim.x * 256) >> 6;
    float w1[64], w2[32];
    #pragma unroll
    for (int j = 0; j < 64; ++j) w1[j] = W1[(h * 64 + j) * 32 + c];
    #pragma unroll
    for (int j = 0; j < 32; ++j) w2[j] = W2[j * 64 + lane];
    float b1c = b1[c], b2l = b2[lane];
    for (int n = wid; n < NN; n += nwaves) {
        float x0 = nf[(size_t)n * 128 + lane];
        float x1 = nf[(size_t)n * 128 + 64 + lane];
        float s0 = 0.f, s1 = 0.f, s2 = 0.f, s3 = 0.f;
        #pragma unroll
        for (int j = 0; j < 16; ++j) {
            float xa0 = h ? rlf(x1, j)      : rlf(x0, j);
            float xa1 = h ? rlf(x1, j + 16) : rlf(x0, j + 16);
            float xa2 = h ? rlf(x1, j + 32) : rlf(x0, j + 32);
            float xa3 = h ? rlf(x1, j + 48) : rlf(x0, j + 48);
            s0 = fmaf(xa0, w1[j], s0);
            s1 = fmaf(xa1, w1[j + 16], s1);
            s2 = fmaf(xa2, w1[j + 32], s2);
            s3 = fmaf(xa3, w1[j + 48], s3);
        }
        float s = (s0 + s1) + (s2 + s3);
        s += __shfl_xor(s, 32, 64);           // combine k-halves
        float hv = fmaxf(s + b1c, 0.f);       // lane l holds h1[l&31]
        float o0 = 0.f, o1 = 0.f, o2 = 0.f, o3 = 0.f;
        #pragma unroll
        for (int j = 0; j < 8; ++j) {
            o0 = fmaf(rlf(hv, j),      w2[j],      o0);
            o1 = fmaf(rlf(hv, j + 8),  w2[j + 8],  o1);
            o2 = fmaf(rlf(hv, j + 16), w2[j + 16], o2);
            o3 = fmaf(rlf(hv, j + 24), w2[j + 24], o3);
        }
        float o = b2l + (o0 + o1) + (o2 + o3);
        Xs[(size_t)n * 64 + lane] = disq[n] * o;
    }
}

// ---------------- fused GCN layer ----------------
// agg = Xs[n] + sum_{e in row n} Xs[esrc[e]]       (gather, lane = channel)
// t   = disq[n] * (agg @ W)[lane] + b[lane]
// v   = lrelu(t) [+ res*sq[n]]
// XsOut[n] = disq[n] * v
__global__ __launch_bounds__(256) void k_conv(
    const float* __restrict__ Xs, const int* __restrict__ rowptr,
    const int* __restrict__ esrc, const float* __restrict__ disq,
    const float* __restrict__ sq, const float* __restrict__ W,
    const float* __restrict__ b, const float* __restrict__ res,
    float* __restrict__ XsOut) {
    int lane = threadIdx.x & 63;
    int wid = (blockIdx.x * 256 + threadIdx.x) >> 6;
    int nwaves = (gridDim.x * 256) >> 6;
    float wcol[64];
    #pragma unroll
    for (int k = 0; k < 64; ++k) wcol[k] = W[k * 64 + lane];
    float bl = b[lane];
    for (int n = wid; n < NN; n += nwaves) {
        int beg = rowptr[n], end = rowptr[n + 1];
        float agg = Xs[(size_t)n * 64 + lane];  // self-loop
        for (int base = beg; base < end; base += 64) {
            int cnt = min(64, end - base);
            int idx = (lane < cnt) ? esrc[base + lane] : 0;
            int j = 0;
            for (; j + 4 <= cnt; j += 4) {
                int s0 = __builtin_amdgcn_readlane(idx, j);
                int s1 = __builtin_amdgcn_readlane(idx, j + 1);
                int s2 = __builtin_amdgcn_readlane(idx, j + 2);
                int s3 = __builtin_amdgcn_readlane(idx, j + 3);
                float h0 = Xs[(size_t)s0 * 64 + lane];
                float h1 = Xs[(size_t)s1 * 64 + lane];
                float h2 = Xs[(size_t)s2 * 64 + lane];
                float h3 = Xs[(size_t)s3 * 64 + lane];
                agg += (h0 + h1) + (h2 + h3);
            }
            for (; j < cnt; ++j) {
                int s = __builtin_amdgcn_readlane(idx, j);
                agg += Xs[(size_t)s * 64 + lane];
            }
        }
        float a0 = 0.f, a1 = 0.f, a2 = 0.f, a3 = 0.f;
        #pragma unroll
        for (int k = 0; k < 16; ++k) {
            a0 = fmaf(rlf(agg, k),      wcol[k],      a0);
            a1 = fmaf(rlf(agg, k + 16), wcol[k + 16], a1);
            a2 = fmaf(rlf(agg, k + 32), wcol[k + 32], a2);
            a3 = fmaf(rlf(agg, k + 48), wcol[k + 48], a3);
        }
        float dn = disq[n];
        float t = dn * ((a0 + a1) + (a2 + a3)) + bl;
        float v = (t >= 0.f) ? t : 0.2f * t;
        if (res) v += res[(size_t)n * 64 + lane] * sq[n];
        XsOut[(size_t)n * 64 + lane] = dn * v;
    }
}

// ---------------- conv4 fused with residual + final 64->2 projection ----
__global__ __launch_bounds__(256) void k_conv_final(
    const float* __restrict__ Xs, const int* __restrict__ rowptr,
    const int* __restrict__ esrc, const float* __restrict__ disq,
    const float* __restrict__ sq, const float* __restrict__ W,
    const float* __restrict__ b, const float* __restrict__ res,
    const float* __restrict__ FW, const float* __restrict__ fb,
    float* __restrict__ out) {
    int lane = threadIdx.x & 63;
    int wid = (blockIdx.x * 256 + threadIdx.x) >> 6;
    int nwaves = (gridDim.x * 256) >> 6;
    float wcol[64];
    #pragma unroll
    for (int k = 0; k < 64; ++k) wcol[k] = W[k * 64 + lane];
    float bl = b[lane];
    float fw0 = FW[lane * 2 + 0], fw1 = FW[lane * 2 + 1];
    float fb0 = fb[0], fb1 = fb[1];
    for (int n = wid; n < NN; n += nwaves) {
        int beg = rowptr[n], end = rowptr[n + 1];
        float agg = Xs[(size_t)n * 64 + lane];
        for (int base = beg; base < end; base += 64) {
            int cnt = min(64, end - base);
            int idx = (lane < cnt) ? esrc[base + lane] : 0;
            int j = 0;
            for (; j + 4 <= cnt; j += 4) {
                int s0 = __builtin_amdgcn_readlane(idx, j);
                int s1 = __builtin_amdgcn_readlane(idx, j + 1);
                int s2 = __builtin_amdgcn_readlane(idx, j + 2);
                int s3 = __builtin_amdgcn_readlane(idx, j + 3);
                float h0 = Xs[(size_t)s0 * 64 + lane];
                float h1 = Xs[(size_t)s1 * 64 + lane];
                float h2 = Xs[(size_t)s2 * 64 + lane];
                float h3 = Xs[(size_t)s3 * 64 + lane];
                agg += (h0 + h1) + (h2 + h3);
            }
            for (; j < cnt; ++j) {
                int s = __builtin_amdgcn_readlane(idx, j);
                agg += Xs[(size_t)s * 64 + lane];
            }
        }
        float a0 = 0.f, a1 = 0.f, a2 = 0.f, a3 = 0.f;
        #pragma unroll
        for (int k = 0; k < 16; ++k) {
            a0 = fmaf(rlf(agg, k),      wcol[k],      a0);
            a1 = fmaf(rlf(agg, k + 16), wcol[k + 16], a1);
            a2 = fmaf(rlf(agg, k + 32), wcol[k + 32], a2);
            a3 = fmaf(rlf(agg, k + 48), wcol[k + 48], a3);
        }
        float t = disq[n] * ((a0 + a1) + (a2 + a3)) + bl;
        float v = t + res[(size_t)n * 64 + lane] * sq[n];  // out4 (no lrelu)
        float p0 = v * fw0;
        float p1 = v * fw1;
        for (int off = 32; off; off >>= 1) {
            p0 += __shfl_xor(p0, off, 64);
            p1 += __shfl_xor(p1, off, 64);
        }
        if (lane == 0) {
            out[n * 2 + 0] = p0 + fb0;
            out[n * 2 + 1] = p1 + fb1;
        }
    }
}

extern "C" void kernel_launch(void* const* d_in, const int* in_sizes, int n_in,
                              void* d_out, int out_size, void* d_ws, size_t ws_size,
                              hipStream_t stream) {
    const float* nf   = (const float*)d_in[0];
    const int*   ei   = (const int*)d_in[1];
    const float* fc1W = (const float*)d_in[2];
    const float* fc1b = (const float*)d_in[3];
    const float* fc2W = (const float*)d_in[4];
    const float* fc2b = (const float*)d_in[5];
    const float* cW[4] = {(const float*)d_in[6], (const float*)d_in[8],
                          (const float*)d_in[10], (const float*)d_in[12]};
    const float* cb[4] = {(const float*)d_in[7], (const float*)d_in[9],
                          (const float*)d_in[11], (const float*)d_in[13]};
    const float* fW = (const float*)d_in[14];
    const float* fb = (const float*)d_in[15];
    const int* src = ei;
    const int* dst = ei + NE;

    float* ws     = (float*)d_ws;
    float* disq   = ws;                          // 50048 f
    float* sq     = disq + 50048;                // 50048 f
    int*   cnt    = (int*)(sq + 50048);          // 50048 i (histogram, then cursor)
    int*   rowptr = cnt + 50048;                 // 50056 i
    int*   esrc   = rowptr + 50056;              // 800000 i
    float* A      = (float*)(esrc + 800000);     // NN*64 f
    float* B      = A + (size_t)NN * 64;         // NN*64 f
    float* C      = B + (size_t)NN * 64;         // NN*64 f

    // ---- CSR build (once, shared by all 4 convs) ----
    hipMemsetAsync(cnt, 0, 50048 * sizeof(int), stream);
    k_hist<<<(NE + 255) / 256, 256, 0, stream>>>(dst, cnt);
    k_disq<<<(NN + 255) / 256, 256, 0, stream>>>(cnt, disq, sq);
    k_scan<<<1, 1024, 0, stream>>>(cnt, rowptr);
    hipMemsetAsync(cnt, 0, 50048 * sizeof(int), stream);
    k_fill<<<(NE + 255) / 256, 256, 0, stream>>>(src, dst, rowptr, cnt, esrc);

    // ---- fc stack -> A (= Xs0, pre-scaled) ----
    k_fc<<<1024, 256, 0, stream>>>(nf, fc1W, fc1b, fc2W, fc2b, disq, A);

    // conv1: Xs1 -> B
    k_conv<<<1024, 256, 0, stream>>>(A, rowptr, esrc, disq, sq, cW[0], cb[0], nullptr, B);
    // conv2: Xs2 = disq*(lrelu(.)+out1) -> C   (residual from B)
    k_conv<<<1024, 256, 0, stream>>>(B, rowptr, esrc, disq, sq, cW[1], cb[1], B, C);
    // conv3: Xs3 -> A  (Xs0 dead)
    k_conv<<<1024, 256, 0, stream>>>(C, rowptr, esrc, disq, sq, cW[2], cb[2], nullptr, A);
    // conv4 + residual(out2 from C) + final projection -> d_out
    k_conv_final<<<1024, 256, 0, stream>>>(A, rowptr, esrc, disq, sq, cW[3], cb[3], C,
                                           fW, fb, (float*)d_out);
}